// Round 2
// baseline (307.464 us; speedup 1.0000x reference)
//
#include <hip/hip_runtime.h>
#include <stdint.h>

#define BB   16384
#define SS   50
#define DD   64
#define NH1  80
#define NB   16          // batches per workgroup
#define MT   50          // 16-row M-tiles per WG (NB*SS/16)

// workspace layout (shorts/floats), all 16B aligned
#define WS_UVW_SHORTS   (30*64*8)            // 15360 shorts = 30720 B
#define WS_W2_SHORTS    (48*104)             // 4992 shorts  = 9984 B
#define WS_W2_OFF       WS_UVW_SHORTS
#define WS_QP_BYTE_OFF  (2*(WS_UVW_SHORTS+WS_W2_SHORTS))  // 40704 B
#define WS_QP_FLOATS    (SS*DD)              // 3200 floats = 12800 B

typedef short bf16x8 __attribute__((ext_vector_type(8)));
typedef float f32x4  __attribute__((ext_vector_type(4)));

__device__ inline short f2bf(float x) {
    union { float f; uint32_t u; } v; v.f = x;
    uint32_t r = (v.u + 0x7FFFu + ((v.u >> 16) & 1u)) >> 16;
    return (short)r;
}
__device__ inline float fexp(float x)  { return __builtin_amdgcn_exp2f(x * 1.44269504f); }
__device__ inline float fsig(float x)  { return __builtin_amdgcn_rcpf(1.f + fexp(-x)); }

// ---------------- pre-kernel: build weight images once ----------------
__global__ __launch_bounds__(256) void i2i_prep(
    const float* __restrict__ pos, const float* __restrict__ Wq,
    const float* __restrict__ bq,  const float* __restrict__ W1,
    const float* __restrict__ W2,  short* __restrict__ ws_s,
    float* __restrict__ qp)
{
    int gid = blockIdx.x * 256 + threadIdx.x;
    if (gid < 1920) {
        // UVW B-fragments: frag = t*6+ks, lane layout matches main kernel
        int frag = gid >> 6, lane = gid & 63;
        int t = frag / 6, ks = frag % 6;
        int i16 = lane & 15, g = lane >> 4;
        int h = 16*t + i16;
        int kbase = 32*ks + 8*g;
        short tmp[8];
        #pragma unroll
        for (int j = 0; j < 8; ++j) {
            int k = kbase + j;
            float v;
            if (k < 64)       v = W1[k*NH1 + h] + W1[(128+k)*NH1 + h];   // U = W1a+W1c
            else if (k < 128) v = W1[k*NH1 + h] - W1[(k+64)*NH1 + h];    // V = W1b-W1c
            else              v = W1[(k+64)*NH1 + h];                    // W = W1d
            tmp[j] = f2bf(v);
        }
        *(bf16x8*)&ws_s[gid*8] = *(bf16x8*)tmp;
    } else if (gid < 1920 + WS_W2_SHORTS) {
        int idx = gid - 1920;
        int c = idx / 104, kk = idx % 104;
        float v = (c < 40 && kk < 80) ? W2[kk*40 + c] : 0.f;
        ws_s[WS_W2_OFF + idx] = f2bf(v);
    } else if (gid < 1920 + WS_W2_SHORTS + WS_QP_FLOATS) {
        int idx = gid - 1920 - WS_W2_SHORTS;
        int s = idx >> 6, d = idx & 63;
        float acc = bq[d];
        #pragma unroll
        for (int p = 0; p < 4; ++p) acc += pos[s*4 + p] * Wq[(64+p)*64 + d];
        qp[idx] = acc;
    }
}

// ---------------- main kernel ----------------
__global__ __launch_bounds__(256, 4) void i2i_kernel(
    const float* __restrict__ target, const float* __restrict__ seq,
    const int*   __restrict__ mask,   const float* __restrict__ Wq,
    const float* __restrict__ alpha,  const float* __restrict__ b1,
    const float* __restrict__ b2,     const float* __restrict__ W3,
    const float* __restrict__ b3,     const short* __restrict__ ws_s,
    const float* __restrict__ qp,     float* __restrict__ out)
{
    // LDS: 9984 + 4352 + 3328 + 13312 = 30976 B  -> 4 blocks/CU at VGPR<=128
    __shared__ short w2T[48][104];      // [c][k] W2^T zero-padded
    __shared__ float qtLDS[16][68];     // target @ Wq[:64]
    __shared__ float scores[16][52];    // raw scores, then softmax p
    __shared__ short h1buf[4][16][104]; // per-wave h1 tile (cols 80..95 zero)

    const int tid  = threadIdx.x;
    const int wg   = blockIdx.x;
    const int b0   = wg * NB;
    const int lane = tid & 63;
    const int wv   = tid >> 6;

    // ---------------- phase 0: light LDS build ----------------
    for (int o = tid; o < WS_W2_SHORTS/2; o += 256)
        ((int*)w2T)[o] = ((const int*)&ws_s[WS_W2_OFF])[o];
    for (int o = tid; o < 4*16*16; o += 256)            // zero h1 K-pad cols
        h1buf[o >> 8][(o >> 4) & 15][80 + (o & 15)] = 0;
    {   // qt[b] = target[b] @ Wq[:64]  (fp32)
        int d = tid & 63, l0 = tid >> 6;
        for (int lb = l0; lb < NB; lb += 4) {
            const float* trow = target + (size_t)(b0 + lb) * DD;
            float acc = 0.f;
            #pragma unroll 8
            for (int c = 0; c < DD; ++c) acc += trow[c] * Wq[c*DD + d];
            qtLDS[lb][d] = acc;
        }
    }

    const int i16 = lane & 15;
    const int g   = lane >> 4;
    const int dA  = 8 * g, dB = 32 + 8 * g;

    // hoist all UVW B-fragments into registers (coalesced loads from ws)
    bf16x8 bU[5][6];
    #pragma unroll
    for (int t = 0; t < 5; ++t)
        #pragma unroll
        for (int ks = 0; ks < 6; ++ks)
            bU[t][ks] = *(const bf16x8*)&ws_s[((t*6+ks)*64 + lane)*8];

    float b1v[5], b2v[3], w3v[3];
    #pragma unroll
    for (int t = 0; t < 5; ++t) b1v[t] = b1[i16 + 16*t];
    #pragma unroll
    for (int t = 0; t < 3; ++t) {
        int c = i16 + 16*t;
        b2v[t] = (c < 40) ? b2[c] : 0.f;
        w3v[t] = (c < 40) ? W3[c] : 0.f;
    }
    const float b3v = b3[0];
    __syncthreads();

    // ---------------- phase 1: main loop ----------------
    #pragma unroll 1
    for (int mt = wv; mt < MT; mt += 4) {
        const int rloc = mt*16 + i16;
        const int lb   = rloc / 50;
        const int s    = rloc - lb*50;
        const int R    = wg*800 + rloc;
        const float* srow = seq + (size_t)R * DD;
        const float* qprow = qp + s*DD;

        bf16x8 a[6];
        #pragma unroll
        for (int c = 0; c < 4; ++c) {
            const int d0 = (c < 2 ? dA : dB) + (c & 1) * 4;
            const int fi = c >> 1;
            f32x4 x  = *(const f32x4*)&qtLDS[lb][d0] + *(const f32x4*)&qprow[d0];
            f32x4 al = *(const f32x4*)&alpha[d0];
            f32x4 sq = *(const f32x4*)&srow[d0];
            #pragma unroll
            for (int j = 0; j < 4; ++j) {
                const int li = (c & 1)*4 + j;
                float xx = x[j];
                float qv = xx >= 0.f ? xx : al[j]*xx;   // PReLU
                float kv = sq[j];
                a[0+fi][li] = f2bf(qv);
                a[2+fi][li] = f2bf(kv);
                a[4+fi][li] = f2bf(qv*kv);
            }
        }

        // pre1 = feat(192) @ UVW -> [16 rows][80]
        f32x4 acc1[5];
        #pragma unroll
        for (int t = 0; t < 5; ++t) {
            f32x4 c = {0.f,0.f,0.f,0.f};
            #pragma unroll
            for (int ks = 0; ks < 6; ++ks)
                c = __builtin_amdgcn_mfma_f32_16x16x32_bf16(a[ks], bU[t][ks], c, 0, 0, 0);
            acc1[t] = c;
        }
        // sigmoid -> h1 (bf16) into per-wave LDS, C-layout: row=4g+ii, col=i16+16t
        #pragma unroll
        for (int t = 0; t < 5; ++t)
            #pragma unroll
            for (int ii = 0; ii < 4; ++ii)
                h1buf[wv][4*g + ii][i16 + 16*t] = f2bf(fsig(acc1[t][ii] + b1v[t]));
        asm volatile("s_waitcnt lgkmcnt(0)" ::: "memory");

        // h2 = sigmoid(h1 @ W2)  (K=96 padded)
        f32x4 acc2[3];
        #pragma unroll
        for (int t = 0; t < 3; ++t) acc2[t] = (f32x4){0.f,0.f,0.f,0.f};
        #pragma unroll
        for (int ks = 0; ks < 3; ++ks) {
            bf16x8 a2 = *(const bf16x8*)&h1buf[wv][i16][32*ks + 8*g];
            #pragma unroll
            for (int t = 0; t < 3; ++t) {
                bf16x8 bw = *(const bf16x8*)&w2T[16*t + i16][32*ks + 8*g];
                acc2[t] = __builtin_amdgcn_mfma_f32_16x16x32_bf16(a2, bw, acc2[t], 0, 0, 0);
            }
        }
        // score rows 4g+ii: sum over cols of sigmoid(h2)*W3
        float sc[4];
        #pragma unroll
        for (int ii = 0; ii < 4; ++ii) {
            float v = 0.f;
            #pragma unroll
            for (int t = 0; t < 3; ++t)
                v += fsig(acc2[t][ii] + b2v[t]) * w3v[t];
            sc[ii] = v;
        }
        #pragma unroll
        for (int off = 1; off < 16; off <<= 1)
            #pragma unroll
            for (int ii = 0; ii < 4; ++ii)
                sc[ii] += __shfl_xor(sc[ii], off, 64);
        if (i16 == 0) {
            #pragma unroll
            for (int ii = 0; ii < 4; ++ii) {
                int row = mt*16 + 4*g + ii;
                int lb2 = row / 50, s2 = row - lb2*50;
                scores[lb2][s2] = sc[ii] + b3v;
            }
        }
    }
    __syncthreads();

    // ---------------- phase 2: masked softmax + weighted sum ----------------
    for (int lb = wv*4; lb < wv*4 + 4; ++lb) {
        const int b = b0 + lb;
        float sval = 0.f; int mval = 0;
        if (lane < SS) { sval = scores[lb][lane]; mval = mask[b*SS + lane]; }
        float ms = (lane < SS) ? (mval != 0 ? sval : -1e9f) : -INFINITY;
        float M = ms;
        #pragma unroll
        for (int off = 1; off < 64; off <<= 1) M = fmaxf(M, __shfl_xor(M, off, 64));
        float e = fexp(ms - M);                    // -inf lanes -> 0
        float Ssum = e;
        #pragma unroll
        for (int off = 1; off < 64; off <<= 1) Ssum += __shfl_xor(Ssum, off, 64);
        float p = e * __builtin_amdgcn_rcpf(Ssum);
        float rel = (lane < SS && mval != 0) ? sval : 0.f;
        #pragma unroll
        for (int off = 1; off < 64; off <<= 1) rel += __shfl_xor(rel, off, 64);
        if (lane < SS) scores[lb][lane] = p;
        asm volatile("s_waitcnt lgkmcnt(0)" ::: "memory");

        const float* sb = seq + (size_t)b * SS * DD;
        float accd = 0.f;
        #pragma unroll 10
        for (int s = 0; s < SS; ++s)
            accd += scores[lb][s] * sb[s*DD + lane];
        out[(size_t)b * DD + lane] = accd;
        if (lane == 0) out[(size_t)BB * DD + b] = rel;
    }
}

extern "C" void kernel_launch(void* const* d_in, const int* in_sizes, int n_in,
                              void* d_out, int out_size, void* d_ws, size_t ws_size,
                              hipStream_t stream) {
    const float* target = (const float*)d_in[0];
    const float* seq    = (const float*)d_in[1];
    const int*   mask   = (const int*)d_in[2];
    const float* pos    = (const float*)d_in[3];
    const float* Wq     = (const float*)d_in[4];
    const float* bq     = (const float*)d_in[5];
    const float* alpha  = (const float*)d_in[6];
    const float* W1     = (const float*)d_in[7];
    const float* b1     = (const float*)d_in[8];
    const float* W2     = (const float*)d_in[9];
    const float* b2     = (const float*)d_in[10];
    const float* W3     = (const float*)d_in[11];
    const float* b3     = (const float*)d_in[12];
    float* outp = (float*)d_out;

    short* ws_s = (short*)d_ws;
    float* qp   = (float*)((char*)d_ws + WS_QP_BYTE_OFF);

    hipLaunchKernelGGL(i2i_prep, dim3(40), dim3(256), 0, stream,
                       pos, Wq, bq, W1, W2, ws_s, qp);
    hipLaunchKernelGGL(i2i_kernel, dim3(BB / NB), dim3(256), 0, stream,
                       target, seq, mask, Wq, alpha, b1, b2, W3, b3, ws_s, qp, outp);
}

// Round 3
// 125.507 us; speedup vs baseline: 2.4498x; 2.4498x over previous
//
#include <hip/hip_runtime.h>
#include <stdint.h>

#define BB   16384
#define SS   50
#define DD   64
#define NH1  80
#define NB   16          // batches per workgroup
#define MT   50          // 16-row M-tiles per WG (NB*SS/16)

// workspace layout
#define WS_UVW_SHORTS   (30*64*8)                 // 15360 shorts (30 frags)
#define WS_W2F_OFF      WS_UVW_SHORTS             // 9 frags x 64 lanes x 8
#define WS_W2F_SHORTS   (9*64*8)                  // 4608 shorts
#define WS_QP_BYTE_OFF  (2*(WS_UVW_SHORTS+WS_W2F_SHORTS))  // 39936 B
#define WS_QP_FLOATS    (SS*DD)                   // 3200 floats

typedef short bf16x8 __attribute__((ext_vector_type(8)));
typedef float f32x4  __attribute__((ext_vector_type(4)));
typedef int   i32x4  __attribute__((ext_vector_type(4)));

__device__ inline short f2bf(float x) {
    union { float f; uint32_t u; } v; v.f = x;
    uint32_t r = (v.u + 0x7FFFu + ((v.u >> 16) & 1u)) >> 16;
    return (short)r;
}
__device__ inline float fexp(float x)  { return __builtin_amdgcn_exp2f(x * 1.44269504f); }
__device__ inline float fsig(float x)  { return __builtin_amdgcn_rcpf(1.f + fexp(-x)); }

// ---------------- pre-kernel: build weight images once ----------------
__global__ __launch_bounds__(256) void i2i_prep(
    const float* __restrict__ pos, const float* __restrict__ Wq,
    const float* __restrict__ bq,  const float* __restrict__ W1,
    const float* __restrict__ W2,  short* __restrict__ ws_s,
    float* __restrict__ qp)
{
    int gid = blockIdx.x * 256 + threadIdx.x;
    if (gid < 1920) {
        // UVW B-fragments, frag f = t*6+ks, image layout [f][lane][8]
        int frag = gid >> 6, lane = gid & 63;
        int t = frag / 6, ks = frag % 6;
        int i16 = lane & 15, g = lane >> 4;
        int h = 16*t + i16;
        int kbase = 32*ks + 8*g;
        short tmp[8];
        #pragma unroll
        for (int j = 0; j < 8; ++j) {
            int k = kbase + j;
            float v;
            if (k < 64)       v = W1[k*NH1 + h] + W1[(128+k)*NH1 + h];   // U = W1a+W1c
            else if (k < 128) v = W1[k*NH1 + h] - W1[(k+64)*NH1 + h];    // V = W1b-W1c
            else              v = W1[(k+64)*NH1 + h];                    // W = W1d
            tmp[j] = f2bf(v);
        }
        *(bf16x8*)&ws_s[gid*8] = *(bf16x8*)tmp;
    } else if (gid < 1920 + 576) {
        // W2^T fragments, frag f = t*3+ks, zero-padded (c>=40 or k>=80)
        int idx = gid - 1920;
        int frag = idx >> 6, lane = idx & 63;
        int t = frag / 3, ks = frag % 3;
        int i16 = lane & 15, g = lane >> 4;
        int c = 16*t + i16;
        int kbase = 32*ks + 8*g;
        short tmp[8];
        #pragma unroll
        for (int j = 0; j < 8; ++j) {
            int k = kbase + j;
            float v = (c < 40 && k < 80) ? W2[k*40 + c] : 0.f;
            tmp[j] = f2bf(v);
        }
        *(bf16x8*)&ws_s[WS_W2F_OFF + idx*8] = *(bf16x8*)tmp;
    } else if (gid < 1920 + 576 + WS_QP_FLOATS) {
        int idx = gid - 1920 - 576;
        int s = idx >> 6, d = idx & 63;
        float acc = bq[d];
        #pragma unroll
        for (int p = 0; p < 4; ++p) acc += pos[s*4 + p] * Wq[(64+p)*64 + d];
        qp[idx] = acc;
    }
}

// ---------------- main kernel ----------------
__global__ __launch_bounds__(256, 3) void i2i_kernel(
    const float* __restrict__ target, const float* __restrict__ seq,
    const int*   __restrict__ mask,   const float* __restrict__ Wq,
    const float* __restrict__ alpha,  const float* __restrict__ b1,
    const float* __restrict__ b2,     const float* __restrict__ W3,
    const float* __restrict__ b3,     const short* __restrict__ ws_s,
    const float* __restrict__ qp,     float* __restrict__ out)
{
    // LDS: 30720 + 4352 + 3328 + 13312 = 51712 B -> 3 blocks/CU
    __shared__ short uvw[30*512];       // fragment-ordered UVW image
    __shared__ float qtLDS[16][68];     // target @ Wq[:64]
    __shared__ float scores[16][52];    // raw scores, then softmax p
    __shared__ short h1buf[4][16][104]; // per-wave h1 tile (cols 80..95 zero)

    const int tid  = threadIdx.x;
    const int wg   = blockIdx.x;
    const int b0   = wg * NB;
    const int lane = tid & 63;
    const int wv   = tid >> 6;

    // ---------------- phase 0: LDS build (linear copies) ----------------
    #pragma unroll
    for (int o = 0; o < 8; ++o) {       // 30720B = 1920 int4; last partial round
        int idx = tid + o*256;
        if (idx < 1920) ((i32x4*)uvw)[idx] = ((const i32x4*)ws_s)[idx];
    }
    for (int o = tid; o < 4*16*16; o += 256)            // zero h1 K-pad cols
        h1buf[o >> 8][(o >> 4) & 15][80 + (o & 15)] = 0;
    {   // qt[b] = target[b] @ Wq[:64]  (fp32)
        int d = tid & 63, l0 = tid >> 6;
        for (int lb = l0; lb < NB; lb += 4) {
            const float* trow = target + (size_t)(b0 + lb) * DD;
            float acc = 0.f;
            #pragma unroll 8
            for (int c = 0; c < DD; ++c) acc += trow[c] * Wq[c*DD + d];
            qtLDS[lb][d] = acc;
        }
    }

    const int i16 = lane & 15;
    const int g   = lane >> 4;
    const int dA  = 8 * g, dB = 32 + 8 * g;

    // W2 fragments in registers (36 VGPR)
    bf16x8 bw2[3][3];
    #pragma unroll
    for (int t = 0; t < 3; ++t)
        #pragma unroll
        for (int ks = 0; ks < 3; ++ks)
            bw2[t][ks] = *(const bf16x8*)&ws_s[WS_W2F_OFF + ((t*3+ks)*64 + lane)*8];

    float b1v[5], b2v[3], w3v[3];
    #pragma unroll
    for (int t = 0; t < 5; ++t) b1v[t] = b1[i16 + 16*t];
    #pragma unroll
    for (int t = 0; t < 3; ++t) {
        int c = i16 + 16*t;
        b2v[t] = (c < 40) ? b2[c] : 0.f;
        w3v[t] = (c < 40) ? W3[c] : 0.f;
    }
    const float b3v = b3[0];
    __syncthreads();

    // ---------------- phase 1: main loop ----------------
    #pragma unroll 1
    for (int mt = wv; mt < MT; mt += 4) {
        const int rloc = mt*16 + i16;
        const int lb   = rloc / 50;
        const int s    = rloc - lb*50;
        const int R    = wg*800 + rloc;
        const float* srow = seq + (size_t)R * DD;
        const float* qprow = qp + s*DD;

        bf16x8 a[6];
        #pragma unroll
        for (int c = 0; c < 4; ++c) {
            const int d0 = (c < 2 ? dA : dB) + (c & 1) * 4;
            const int fi = c >> 1;
            f32x4 x  = *(const f32x4*)&qtLDS[lb][d0] + *(const f32x4*)&qprow[d0];
            f32x4 al = *(const f32x4*)&alpha[d0];
            f32x4 sq = *(const f32x4*)&srow[d0];
            #pragma unroll
            for (int j = 0; j < 4; ++j) {
                const int li = (c & 1)*4 + j;
                float xx = x[j];
                float qv = xx >= 0.f ? xx : al[j]*xx;   // PReLU
                float kv = sq[j];
                a[0+fi][li] = f2bf(qv);
                a[2+fi][li] = f2bf(kv);
                a[4+fi][li] = f2bf(qv*kv);
            }
        }

        // pre1 = feat(192) @ UVW -> [16 rows][80]; B frags streamed from LDS
        f32x4 acc1[5];
        #pragma unroll
        for (int t = 0; t < 5; ++t) {
            f32x4 c = {0.f,0.f,0.f,0.f};
            #pragma unroll
            for (int ks = 0; ks < 6; ++ks) {
                bf16x8 bf = *(const bf16x8*)&uvw[(t*6+ks)*512 + lane*8];
                c = __builtin_amdgcn_mfma_f32_16x16x32_bf16(a[ks], bf, c, 0, 0, 0);
            }
            acc1[t] = c;
        }
        // sigmoid -> h1 (bf16) into per-wave LDS, C-layout: row=4g+ii, col=i16+16t
        #pragma unroll
        for (int t = 0; t < 5; ++t)
            #pragma unroll
            for (int ii = 0; ii < 4; ++ii)
                h1buf[wv][4*g + ii][i16 + 16*t] = f2bf(fsig(acc1[t][ii] + b1v[t]));
        asm volatile("s_waitcnt lgkmcnt(0)" ::: "memory");

        // h2 = sigmoid(h1 @ W2)  (K=96 padded)
        f32x4 acc2[3];
        #pragma unroll
        for (int t = 0; t < 3; ++t) acc2[t] = (f32x4){0.f,0.f,0.f,0.f};
        #pragma unroll
        for (int ks = 0; ks < 3; ++ks) {
            bf16x8 a2 = *(const bf16x8*)&h1buf[wv][i16][32*ks + 8*g];
            #pragma unroll
            for (int t = 0; t < 3; ++t)
                acc2[t] = __builtin_amdgcn_mfma_f32_16x16x32_bf16(a2, bw2[t][ks], acc2[t], 0, 0, 0);
        }
        // score rows 4g+ii: sum over cols of sigmoid(h2)*W3
        float sc[4];
        #pragma unroll
        for (int ii = 0; ii < 4; ++ii) {
            float v = 0.f;
            #pragma unroll
            for (int t = 0; t < 3; ++t)
                v += fsig(acc2[t][ii] + b2v[t]) * w3v[t];
            sc[ii] = v;
        }
        #pragma unroll
        for (int off = 1; off < 16; off <<= 1)
            #pragma unroll
            for (int ii = 0; ii < 4; ++ii)
                sc[ii] += __shfl_xor(sc[ii], off, 64);
        if (i16 == 0) {
            #pragma unroll
            for (int ii = 0; ii < 4; ++ii) {
                int row = mt*16 + 4*g + ii;
                int lb2 = row / 50, s2 = row - lb2*50;
                scores[lb2][s2] = sc[ii] + b3v;
            }
        }
    }
    __syncthreads();

    // ---------------- phase 2: masked softmax + weighted sum ----------------
    for (int lb = wv*4; lb < wv*4 + 4; ++lb) {
        const int b = b0 + lb;
        float sval = 0.f; int mval = 0;
        if (lane < SS) { sval = scores[lb][lane]; mval = mask[b*SS + lane]; }
        float ms = (lane < SS) ? (mval != 0 ? sval : -1e9f) : -INFINITY;
        float M = ms;
        #pragma unroll
        for (int off = 1; off < 64; off <<= 1) M = fmaxf(M, __shfl_xor(M, off, 64));
        float e = fexp(ms - M);                    // -inf lanes -> 0
        float Ssum = e;
        #pragma unroll
        for (int off = 1; off < 64; off <<= 1) Ssum += __shfl_xor(Ssum, off, 64);
        float p = e * __builtin_amdgcn_rcpf(Ssum);
        float rel = (lane < SS && mval != 0) ? sval : 0.f;
        #pragma unroll
        for (int off = 1; off < 64; off <<= 1) rel += __shfl_xor(rel, off, 64);
        if (lane < SS) scores[lb][lane] = p;
        asm volatile("s_waitcnt lgkmcnt(0)" ::: "memory");

        const float* sb = seq + (size_t)b * SS * DD;
        float accd = 0.f;
        #pragma unroll 10
        for (int s = 0; s < SS; ++s)
            accd += scores[lb][s] * sb[s*DD + lane];
        out[(size_t)b * DD + lane] = accd;
        if (lane == 0) out[(size_t)BB * DD + b] = rel;
    }
}

extern "C" void kernel_launch(void* const* d_in, const int* in_sizes, int n_in,
                              void* d_out, int out_size, void* d_ws, size_t ws_size,
                              hipStream_t stream) {
    const float* target = (const float*)d_in[0];
    const float* seq    = (const float*)d_in[1];
    const int*   mask   = (const int*)d_in[2];
    const float* pos    = (const float*)d_in[3];
    const float* Wq     = (const float*)d_in[4];
    const float* bq     = (const float*)d_in[5];
    const float* alpha  = (const float*)d_in[6];
    const float* b1     = (const float*)d_in[8];
    const float* W1     = (const float*)d_in[7];
    const float* W2     = (const float*)d_in[9];
    const float* b2     = (const float*)d_in[10];
    const float* W3     = (const float*)d_in[11];
    const float* b3     = (const float*)d_in[12];
    float* outp = (float*)d_out;

    short* ws_s = (short*)d_ws;
    float* qp   = (float*)((char*)d_ws + WS_QP_BYTE_OFF);

    hipLaunchKernelGGL(i2i_prep, dim3(23), dim3(256), 0, stream,
                       pos, Wq, bq, W1, W2, ws_s, qp);
    hipLaunchKernelGGL(i2i_kernel, dim3(BB / NB), dim3(256), 0, stream,
                       target, seq, mask, Wq, alpha, b1, b2, W3, b3, ws_s, qp, outp);
}